// Round 12
// baseline (149.494 us; speedup 1.0000x reference)
//
#include <hip/hip_runtime.h>

#define NN 50000
#define NE 1600000
#define FIN 128
#define FOUT 64
#define SLOPE 0.2f

#define NBC  63              // coarse bins, 800 nodes each (63*800 = 50400)
#define NPC  800
#define CAPC 27500           // coarse cap (mean 25397, sd ~159 -> +13 sigma)
#define NBF  1575            // fine buckets = 63*25, 32 nodes each
#define NPB  32
#define CAPB 1536            // fine cap (mean 1024, sd 32 -> +16 sigma)
#define FBLK 522             // coarse-fill blocks (522*768 quads >= NE/4)
#define CHC4 768             // int4 edge-quads per coarse-fill block (3072 edges)
#define K2PB 16              // fine blocks per coarse bin (1008 total)
#define FINB (NBC * K2PB)
#define GBLK 782             // gemm blocks, 64 nodes each
#define LW   136             // gemm LDS row stride in bf16 units (272 B)

typedef unsigned int u32;
typedef short short8 __attribute__((ext_vector_type(8)));
typedef float f32x4 __attribute__((ext_vector_type(4)));

__device__ __forceinline__ unsigned short f2bf(float f) {   // RTNE
    u32 u = __float_as_uint(f);
    u += 0x7FFFu + ((u >> 16) & 1u);
    return (unsigned short)(u >> 16);
}
__device__ __forceinline__ float bf2f(unsigned short s) {
    return __uint_as_float(((u32)s) << 16);
}

// K1: coarse radix — bin edges by dst/800 into 63 bins, packed src|(dl<<16).
// Per-wave count AND per-wave scatter cursors: scatter atomics collide only
// within a wave (R11 theory: cross-wave LDS cursor contention was the chain).
__global__ __launch_bounds__(256) void fill_k(
        const int* __restrict__ ei, int* __restrict__ ccur,
        u32* __restrict__ cstage) {
    __shared__ int cnt[4][64];               // count phase; becomes per-wave cursor
    const int tid = threadIdx.x, wv = tid >> 6;
    ((int*)cnt)[tid] = 0;
    __syncthreads();
    const int4* sd4 = (const int4*)(ei + NE);
    const int4* ss4 = (const int4*)ei;
    const int lo = blockIdx.x * CHC4, hi = min(NE / 4, lo + CHC4);
    for (int i = lo + tid; i < hi; i += 256) {
        int4 d = sd4[i];
        atomicAdd(&cnt[wv][d.x / NPC], 1);
        atomicAdd(&cnt[wv][d.y / NPC], 1);
        atomicAdd(&cnt[wv][d.z / NPC], 1);
        atomicAdd(&cnt[wv][d.w / NPC], 1);
    }
    __syncthreads();
    if (tid < 64) {                          // one global atomic per bin; then
        int c0 = cnt[0][tid], c1 = cnt[1][tid];      // per-wave absolute starts
        int c2 = cnt[2][tid], c3 = cnt[3][tid];
        int tot = c0 + c1 + c2 + c3;
        int base = tot ? atomicAdd(&ccur[tid], tot) : 0;
        cnt[0][tid] = base;
        cnt[1][tid] = base + c0;
        cnt[2][tid] = base + c0 + c1;
        cnt[3][tid] = base + c0 + c1 + c2;
    }
    __syncthreads();
    for (int i = lo + tid; i < hi; i += 256) {
        int4 d = sd4[i];
        int4 s = ss4[i];
        int b, pos;
        b = d.x / NPC; pos = atomicAdd(&cnt[wv][b], 1);
        if (pos < CAPC) cstage[b * CAPC + pos] = (u32)s.x | ((u32)(d.x - b * NPC) << 16);
        b = d.y / NPC; pos = atomicAdd(&cnt[wv][b], 1);
        if (pos < CAPC) cstage[b * CAPC + pos] = (u32)s.y | ((u32)(d.y - b * NPC) << 16);
        b = d.z / NPC; pos = atomicAdd(&cnt[wv][b], 1);
        if (pos < CAPC) cstage[b * CAPC + pos] = (u32)s.z | ((u32)(d.z - b * NPC) << 16);
        b = d.w / NPC; pos = atomicAdd(&cnt[wv][b], 1);
        if (pos < CAPC) cstage[b * CAPC + pos] = (u32)s.w | ((u32)(d.w - b * NPC) << 16);
    }
}

union FgLds {
    unsigned short Wt[64 * LW];              // 17.4 KB (gemm branch)
    int fcnt[4][32];                         // fine branch per-wave counts/cursors
};

// K2: blocks [0, FINB): fine re-bin (coarse bin -> 25 aligned 32-node buckets,
//   K2PB=16 slices/bin, per-wave cursors). blocks [FINB, ..): bf16-MFMA gemm.
__global__ __launch_bounds__(256) void fg_k(
        const u32* __restrict__ cstage, const int* __restrict__ ccur,
        int* __restrict__ fcur, u32* __restrict__ fstage,
        const float* __restrict__ x, const float* __restrict__ W,
        const float* __restrict__ att_s, const float* __restrict__ att_d,
        unsigned short* __restrict__ h, float* __restrict__ a_src,
        float* __restrict__ a_dst) {
    __shared__ FgLds L;
    const int tid = threadIdx.x;

    if (blockIdx.x < FINB) {
        const int bin = blockIdx.x / K2PB, sub = blockIdx.x % K2PB;
        const int size = min(ccur[bin], CAPC);
        const int qs = (size + K2PB - 1) / K2PB;
        const int lo = sub * qs, hi = min(size, lo + qs);
        const u32* src = cstage + (size_t)bin * CAPC;
        const int wv = tid >> 6;
        ((int*)L.fcnt)[tid & 127] = 0;       // zero 128 ints
        __syncthreads();
        for (int i = lo + tid; i < hi; i += 256)
            atomicAdd(&L.fcnt[wv][(src[i] >> 16) >> 5], 1);
        __syncthreads();
        if (tid < 25) {
            int c0 = L.fcnt[0][tid], c1 = L.fcnt[1][tid];
            int c2 = L.fcnt[2][tid], c3 = L.fcnt[3][tid];
            int tot = c0 + c1 + c2 + c3;
            int base = tot ? atomicAdd(&fcur[bin * 25 + tid], tot) : 0;
            L.fcnt[0][tid] = base;
            L.fcnt[1][tid] = base + c0;
            L.fcnt[2][tid] = base + c0 + c1;
            L.fcnt[3][tid] = base + c0 + c1 + c2;
        }
        __syncthreads();
        for (int i = lo + tid; i < hi; i += 256) {
            u32 w = src[i];
            int dl = w >> 16;                // coarse-local dst [0,800)
            int f = dl >> 5;                 // fine bucket [0,25)
            int pos = atomicAdd(&L.fcnt[wv][f], 1);
            if (pos < CAPB)
                fstage[(size_t)(bin * 25 + f) * CAPB + pos] =
                    (w & 0xFFFFu) | ((u32)(dl & 31) << 16);
        }
    } else {
        unsigned short* Wt = L.Wt;
        const int node0 = (blockIdx.x - FINB) * 64;
        for (int i = tid; i < 128 * 16; i += 256) {   // stage W^T as bf16
            int k = i >> 4, f = (i & 15) * 4;
            float4 w4 = ((const float4*)W)[i];        // W[k][f..f+3]
            Wt[(f + 0) * LW + k] = f2bf(w4.x);
            Wt[(f + 1) * LW + k] = f2bf(w4.y);
            Wt[(f + 2) * LW + k] = f2bf(w4.z);
            Wt[(f + 3) * LW + k] = f2bf(w4.w);
        }
        const int wv = tid >> 6, lane = tid & 63;
        const int q = lane >> 4, mr = lane & 15;
        const int row = node0 + wv * 16 + mr;
        const bool valid = row < NN;
        const float4* x4 = (const float4*)x;

        short8 afr[4];                       // A-frags direct from global
        #pragma unroll
        for (int ks = 0; ks < 4; ++ks) {
            float4 f0 = make_float4(0.f, 0.f, 0.f, 0.f), f1 = f0;
            if (valid) {
                f0 = x4[(size_t)row * 32 + ks * 8 + q * 2];
                f1 = x4[(size_t)row * 32 + ks * 8 + q * 2 + 1];
            }
            short8 a;
            a[0] = (short)f2bf(f0.x); a[1] = (short)f2bf(f0.y);
            a[2] = (short)f2bf(f0.z); a[3] = (short)f2bf(f0.w);
            a[4] = (short)f2bf(f1.x); a[5] = (short)f2bf(f1.y);
            a[6] = (short)f2bf(f1.z); a[7] = (short)f2bf(f1.w);
            afr[ks] = a;
        }
        __syncthreads();

        f32x4 acc[4] = {{0,0,0,0},{0,0,0,0},{0,0,0,0},{0,0,0,0}};
        #pragma unroll
        for (int ks = 0; ks < 4; ++ks) {
            #pragma unroll
            for (int nt = 0; nt < 4; ++nt) {
                short8 b = *(const short8*)(Wt + (nt * 16 + mr) * LW + ks * 32 + q * 8);
                acc[nt] = __builtin_amdgcn_mfma_f32_16x16x32_bf16(afr[ks], b, acc[nt], 0, 0, 0);
            }
        }
        float atts[4], attd[4];
        #pragma unroll
        for (int nt = 0; nt < 4; ++nt) {
            atts[nt] = att_s[nt * 16 + mr];
            attd[nt] = att_d[nt * 16 + mr];
        }
        #pragma unroll
        for (int r = 0; r < 4; ++r) {
            int node = node0 + wv * 16 + q * 4 + r;   // C-layout row
            float ps = 0.f, pd = 0.f;
            #pragma unroll
            for (int nt = 0; nt < 4; ++nt) {
                float v = acc[nt][r];
                if (node < NN) h[(size_t)node * 64 + nt * 16 + mr] = f2bf(v);
                ps += v * atts[nt];
                pd += v * attd[nt];
            }
            #pragma unroll
            for (int off = 8; off > 0; off >>= 1) {
                ps += __shfl_xor(ps, off);
                pd += __shfl_xor(pd, off);
            }
            if (mr == 0 && node < NN) { a_src[node] = ps; a_dst[node] = pd; }
        }
    }
}

// K3: one block per 32-node fine bucket: node-local CSR in LDS, then one
// 16-lane quad per node; gather loop unrolled 8 deep for latency hiding.
__global__ __launch_bounds__(256) void agg_k(
        const u32* __restrict__ staging, const int* __restrict__ bcur,
        const float* __restrict__ a_src, const float* __restrict__ a_dst,
        const ushort4* __restrict__ h4, const float* __restrict__ bias,
        float* __restrict__ out) {
    const int bkt = blockIdx.x;
    const int node0 = bkt << 5;
    if (node0 >= NN) return;                 // tail buckets (>50000)
    const int nNodes = min(NPB, NN - node0);
    const int bsize = min(bcur[bkt], CAPB);
    const u32* stg = staging + (size_t)bkt * CAPB;
    const int tid = threadIdx.x, wv = tid >> 6, lane = tid & 63;

    __shared__ u32 pk[CAPB];                 // packed; aliased as evals
    __shared__ unsigned short ssrc[CAPB];
    __shared__ int lcnt[NPB];
    __shared__ int lbase[NPB + 1];
    __shared__ int lcur[NPB];
    float* evals = (float*)pk;

    for (int j = tid; j < bsize; j += 256) pk[j] = stg[j];
    if (tid < NPB) lcnt[tid] = 0;
    __syncthreads();
    for (int j = tid; j < bsize; j += 256)
        atomicAdd(&lcnt[pk[j] >> 16], 1);
    __syncthreads();
    if (tid < 64) {                          // wave-0 scan (NPB=32)
        int v = (tid < NPB) ? lcnt[tid] : 0;
        #pragma unroll
        for (int off = 1; off < NPB; off <<= 1) {
            int u = __shfl_up(v, off);
            if (tid >= off) v += u;
        }
        if (tid < NPB) lbase[tid + 1] = v;
        if (tid == 0) lbase[0] = 0;
    }
    if (tid >= 64 && tid < 64 + NPB) lcur[tid - 64] = 0;
    __syncthreads();
    for (int j = tid; j < bsize; j += 256) {
        u32 w = pk[j];
        int ld = w >> 16;
        int pos = lbase[ld] + atomicAdd(&lcur[ld], 1);
        ssrc[pos] = (unsigned short)(w & 0xFFFFu);
    }
    __syncthreads();                         // pk dead; evals alias live

    const int q = lane >> 4, ql = lane & 15;
    const float4 b4 = ((const float4*)bias)[ql];
    #pragma unroll
    for (int rnd = 0; rnd < 2; ++rnd) {
        const int ln = rnd * 16 + wv * 4 + q;
        if (ln >= nNodes) continue;
        const int n = node0 + ln;
        const int st = lbase[ln], deg = lbase[ln + 1] - st;
        const float ad = a_dst[n];
        float es = a_src[n] + ad; es = es > 0.f ? es : SLOPE * es;
        const float ps = __expf(es);         // self-loop term
        float sum = 0.f;
        for (int j = ql; j < deg; j += 16) {
            int s = ssrc[st + j];
            float e = a_src[s] + ad; e = e > 0.f ? e : SLOPE * e;
            float pe = __expf(e);
            evals[st + j] = pe;
            sum += pe;
        }
        sum += __shfl_xor(sum, 8); sum += __shfl_xor(sum, 4);
        sum += __shfl_xor(sum, 2); sum += __shfl_xor(sum, 1);
        const float inv = 1.f / (sum + ps);

        ushort4 hs = h4[(size_t)n * 16 + ql];
        float a0 = ps * bf2f(hs.x), a1 = ps * bf2f(hs.y);
        float a2 = ps * bf2f(hs.z), a3 = ps * bf2f(hs.w);
        int j = 0;
        for (; j + 8 <= deg; j += 8) {       // 8 independent gathers in flight
            ushort4 v[8];
            float ev[8];
            #pragma unroll
            for (int t = 0; t < 8; ++t) {
                v[t] = h4[(size_t)ssrc[st + j + t] * 16 + ql];
                ev[t] = evals[st + j + t];
            }
            #pragma unroll
            for (int t = 0; t < 8; ++t) {
                a0 += ev[t] * bf2f(v[t].x); a1 += ev[t] * bf2f(v[t].y);
                a2 += ev[t] * bf2f(v[t].z); a3 += ev[t] * bf2f(v[t].w);
            }
        }
        for (; j < deg; ++j) {
            int s = ssrc[st + j];
            float ev = evals[st + j];
            ushort4 hv = h4[(size_t)s * 16 + ql];
            a0 += ev * bf2f(hv.x); a1 += ev * bf2f(hv.y);
            a2 += ev * bf2f(hv.z); a3 += ev * bf2f(hv.w);
        }
        float4 o;
        o.x = a0 * inv + b4.x; o.x = o.x > 0.f ? o.x : 0.f;
        o.y = a1 * inv + b4.y; o.y = o.y > 0.f ? o.y : 0.f;
        o.z = a2 * inv + b4.z; o.z = o.z > 0.f ? o.z : 0.f;
        o.w = a3 * inv + b4.w; o.w = o.w > 0.f ? o.w : 0.f;
        ((float4*)out)[(size_t)n * 16 + ql] = o;
    }
}

extern "C" void kernel_launch(void* const* d_in, const int* in_sizes, int n_in,
                              void* d_out, int out_size, void* d_ws, size_t ws_size,
                              hipStream_t stream) {
    const float* x     = (const float*)d_in[0];
    const int*   ei    = (const int*)d_in[1];     // int32 (harness converts)
    const float* W     = (const float*)d_in[2];
    const float* att_s = (const float*)d_in[3];
    const float* att_d = (const float*)d_in[4];
    const float* bias  = (const float*)d_in[5];
    float* out = (float*)d_out;

    // ws: h[NN*64] bf16 (6.4MB) | a_src | a_dst (0.4MB) | ccur[64] | fcur[1600]
    //     | cstage[63*27500] u32 (6.9MB) | fstage[1575*1536] u32 (9.7MB)
    unsigned short* h = (unsigned short*)d_ws;
    float* a_src  = (float*)(h + (size_t)NN * 64);
    float* a_dst  = a_src + NN;
    int*   ccur   = (int*)(a_dst + NN);
    int*   fcur   = ccur + 64;
    u32*   cstage = (u32*)(fcur + 1600);
    u32*   fstage = cstage + (size_t)NBC * CAPC;

    hipMemsetAsync(ccur, 0, (64 + 1600) * sizeof(int), stream);  // ccur+fcur

    fill_k<<<FBLK, 256, 0, stream>>>(ei, ccur, cstage);
    fg_k<<<FINB + GBLK, 256, 0, stream>>>(cstage, ccur, fcur, fstage,
                                          x, W, att_s, att_d, h, a_src, a_dst);
    agg_k<<<NBF, 256, 0, stream>>>(fstage, fcur, a_src, a_dst,
                                   (const ushort4*)h, bias, out);
}

// Round 13
// 147.851 us; speedup vs baseline: 1.0111x; 1.0111x over previous
//
#include <hip/hip_runtime.h>

#define NN 50000
#define NE 1600000
#define FIN 128
#define FOUT 64
#define SLOPE 0.2f

#define NBC  63              // coarse bins, 800 nodes each (63*800 = 50400)
#define NPC  800
#define CAPC 27500           // coarse cap (mean 25397, sd ~159 -> +13 sigma)
#define NBF  1575            // fine buckets = 63*25, 32 nodes each
#define NPB  32
#define CAPB 1536            // fine cap (mean 1024, sd 32 -> +16 sigma)
#define FBLK 522             // coarse-fill blocks (tail parallelism: R10 had 261)
#define CHC4 768             // int4 edge-quads per coarse-fill block (3072 edges)
#define GBLK 782             // gemm blocks, 64 nodes each
#define K2PB 8               // fine blocks per coarse bin (504 total)
#define LW   136             // gemm LDS row stride in bf16 units (272 B)

typedef unsigned int u32;
typedef short short8 __attribute__((ext_vector_type(8)));
typedef float f32x4 __attribute__((ext_vector_type(4)));

__device__ __forceinline__ unsigned short f2bf(float f) {   // RTNE
    u32 u = __float_as_uint(f);
    u += 0x7FFFu + ((u >> 16) & 1u);
    return (unsigned short)(u >> 16);
}
__device__ __forceinline__ float bf2f(unsigned short s) {
    return __uint_as_float(((u32)s) << 16);
}

union FusedLds {
    unsigned short Wt[64 * LW];                       // 17.4 KB (gemm branch)
    struct { int cnt[4][64]; int gb[64]; int cur[64]; } f;  // 1.5 KB (fill)
};

// blocks [0, FBLK): coarse radix pass — bin edges by dst/800 into 63 coarse
//   bins, packed src | (dstLocal<<16). Per-wave LDS counts, one global atomic
//   per bin per block, BLOCK-level scatter cursors (R12 lesson: per-wave
//   cursors shorten store runs below a cache line -> write amplification).
// blocks [FBLK, FBLK+GBLK): h = x@W bf16 MFMA + a_src/a_dst (fp32 acc)
__global__ __launch_bounds__(256) void fused_k(
        const float* __restrict__ x, const float* __restrict__ W,
        const float* __restrict__ att_s, const float* __restrict__ att_d,
        const int* __restrict__ ei, int* __restrict__ ccur,
        u32* __restrict__ cstage, unsigned short* __restrict__ h,
        float* __restrict__ a_src, float* __restrict__ a_dst) {
    __shared__ FusedLds L;
    const int tid = threadIdx.x;

    if (blockIdx.x < FBLK) {
        const int wv = tid >> 6;
        ((int*)L.f.cnt)[tid] = 0;                     // 256 ints exactly
        __syncthreads();
        const int4* sd4 = (const int4*)(ei + NE);
        const int4* ss4 = (const int4*)ei;
        const int lo = blockIdx.x * CHC4, hi = min(NE / 4, lo + CHC4);
        for (int i = lo + tid; i < hi; i += 256) {
            int4 d = sd4[i];
            atomicAdd(&L.f.cnt[wv][d.x / NPC], 1);
            atomicAdd(&L.f.cnt[wv][d.y / NPC], 1);
            atomicAdd(&L.f.cnt[wv][d.z / NPC], 1);
            atomicAdd(&L.f.cnt[wv][d.w / NPC], 1);
        }
        __syncthreads();
        if (tid < NBC) {
            int tot = L.f.cnt[0][tid] + L.f.cnt[1][tid]
                    + L.f.cnt[2][tid] + L.f.cnt[3][tid];
            L.f.gb[tid] = tot ? atomicAdd(&ccur[tid], tot) : 0;
            L.f.cur[tid] = 0;
        }
        __syncthreads();
        for (int i = lo + tid; i < hi; i += 256) {
            int4 d = sd4[i];
            int4 s = ss4[i];
            int b, pos;
            b = d.x / NPC; pos = L.f.gb[b] + atomicAdd(&L.f.cur[b], 1);
            if (pos < CAPC) cstage[b * CAPC + pos] = (u32)s.x | ((u32)(d.x - b * NPC) << 16);
            b = d.y / NPC; pos = L.f.gb[b] + atomicAdd(&L.f.cur[b], 1);
            if (pos < CAPC) cstage[b * CAPC + pos] = (u32)s.y | ((u32)(d.y - b * NPC) << 16);
            b = d.z / NPC; pos = L.f.gb[b] + atomicAdd(&L.f.cur[b], 1);
            if (pos < CAPC) cstage[b * CAPC + pos] = (u32)s.z | ((u32)(d.z - b * NPC) << 16);
            b = d.w / NPC; pos = L.f.gb[b] + atomicAdd(&L.f.cur[b], 1);
            if (pos < CAPC) cstage[b * CAPC + pos] = (u32)s.w | ((u32)(d.w - b * NPC) << 16);
        }
    } else {
        unsigned short* Wt = L.Wt;
        const int node0 = (blockIdx.x - FBLK) * 64;
        for (int i = tid; i < 128 * 16; i += 256) {   // stage W^T as bf16
            int k = i >> 4, f = (i & 15) * 4;
            float4 w4 = ((const float4*)W)[i];        // W[k][f..f+3]
            Wt[(f + 0) * LW + k] = f2bf(w4.x);
            Wt[(f + 1) * LW + k] = f2bf(w4.y);
            Wt[(f + 2) * LW + k] = f2bf(w4.z);
            Wt[(f + 3) * LW + k] = f2bf(w4.w);
        }
        const int wv = tid >> 6, lane = tid & 63;
        const int q = lane >> 4, mr = lane & 15;
        const int row = node0 + wv * 16 + mr;
        const bool valid = row < NN;
        const float4* x4 = (const float4*)x;

        short8 afr[4];                                // A-frags direct from global
        #pragma unroll
        for (int ks = 0; ks < 4; ++ks) {
            float4 f0 = make_float4(0.f, 0.f, 0.f, 0.f), f1 = f0;
            if (valid) {
                f0 = x4[(size_t)row * 32 + ks * 8 + q * 2];
                f1 = x4[(size_t)row * 32 + ks * 8 + q * 2 + 1];
            }
            short8 a;
            a[0] = (short)f2bf(f0.x); a[1] = (short)f2bf(f0.y);
            a[2] = (short)f2bf(f0.z); a[3] = (short)f2bf(f0.w);
            a[4] = (short)f2bf(f1.x); a[5] = (short)f2bf(f1.y);
            a[6] = (short)f2bf(f1.z); a[7] = (short)f2bf(f1.w);
            afr[ks] = a;
        }
        __syncthreads();

        f32x4 acc[4] = {{0,0,0,0},{0,0,0,0},{0,0,0,0},{0,0,0,0}};
        #pragma unroll
        for (int ks = 0; ks < 4; ++ks) {
            #pragma unroll
            for (int nt = 0; nt < 4; ++nt) {
                short8 b = *(const short8*)(Wt + (nt * 16 + mr) * LW + ks * 32 + q * 8);
                acc[nt] = __builtin_amdgcn_mfma_f32_16x16x32_bf16(afr[ks], b, acc[nt], 0, 0, 0);
            }
        }
        float atts[4], attd[4];
        #pragma unroll
        for (int nt = 0; nt < 4; ++nt) {
            atts[nt] = att_s[nt * 16 + mr];
            attd[nt] = att_d[nt * 16 + mr];
        }
        #pragma unroll
        for (int r = 0; r < 4; ++r) {
            int node = node0 + wv * 16 + q * 4 + r;   // C-layout row
            float ps = 0.f, pd = 0.f;
            #pragma unroll
            for (int nt = 0; nt < 4; ++nt) {
                float v = acc[nt][r];
                if (node < NN) h[(size_t)node * 64 + nt * 16 + mr] = f2bf(v);
                ps += v * atts[nt];
                pd += v * attd[nt];
            }
            #pragma unroll
            for (int off = 8; off > 0; off >>= 1) {
                ps += __shfl_xor(ps, off);
                pd += __shfl_xor(pd, off);
            }
            if (mr == 0 && node < NN) { a_src[node] = ps; a_dst[node] = pd; }
        }
    }
}

// pass 2: re-bin each coarse bin into its 25 aligned fine buckets (800=25*32).
// K2PB blocks per bin, disjoint slices; runs ~500 B -> near-1x write amp.
__global__ __launch_bounds__(256) void fine_k(
        const u32* __restrict__ cstage, const int* __restrict__ ccur,
        int* __restrict__ fcur, u32* __restrict__ fstage) {
    const int bin = blockIdx.x / K2PB, sub = blockIdx.x % K2PB;
    const int size = min(ccur[bin], CAPC);
    const int qs = (size + K2PB - 1) / K2PB;
    const int lo = sub * qs, hi = min(size, lo + qs);
    const u32* src = cstage + (size_t)bin * CAPC;
    const int tid = threadIdx.x, wv = tid >> 6;

    __shared__ int cnt[4][32];
    __shared__ int gb[32];
    __shared__ int cur[32];
    ((int*)cnt)[tid & 127] = 0;                       // zero 128 ints (2x harmless)
    __syncthreads();
    for (int i = lo + tid; i < hi; i += 256)
        atomicAdd(&cnt[wv][(src[i] >> 16) >> 5], 1);
    __syncthreads();
    if (tid < 25) {
        int tot = cnt[0][tid] + cnt[1][tid] + cnt[2][tid] + cnt[3][tid];
        gb[tid] = tot ? atomicAdd(&fcur[bin * 25 + tid], tot) : 0;
        cur[tid] = 0;
    }
    __syncthreads();
    for (int i = lo + tid; i < hi; i += 256) {
        u32 w = src[i];
        int dl = w >> 16;                             // coarse-local dst [0,800)
        int f = dl >> 5;                              // fine bucket in bin [0,25)
        int pos = gb[f] + atomicAdd(&cur[f], 1);
        if (pos < CAPB)
            fstage[(size_t)(bin * 25 + f) * CAPB + pos] =
                (w & 0xFFFFu) | ((u32)(dl & 31) << 16);
    }
}

// one block per 32-node fine bucket: node-local CSR in LDS, then one 16-lane
// quad per node (lane = 4 features, ushort4 h loads, float4 out store).
__global__ __launch_bounds__(256) void agg_k(
        const u32* __restrict__ staging, const int* __restrict__ bcur,
        const float* __restrict__ a_src, const float* __restrict__ a_dst,
        const ushort4* __restrict__ h4, const float* __restrict__ bias,
        float* __restrict__ out) {
    const int bkt = blockIdx.x;
    const int node0 = bkt << 5;
    if (node0 >= NN) return;                          // tail buckets (>50000)
    const int nNodes = min(NPB, NN - node0);
    const int bsize = min(bcur[bkt], CAPB);
    const u32* stg = staging + (size_t)bkt * CAPB;
    const int tid = threadIdx.x, wv = tid >> 6, lane = tid & 63;

    __shared__ u32 pk[CAPB];                          // packed; aliased as evals
    __shared__ unsigned short ssrc[CAPB];
    __shared__ int lcnt[NPB];
    __shared__ int lbase[NPB + 1];
    __shared__ int lcur[NPB];
    float* evals = (float*)pk;

    for (int j = tid; j < bsize; j += 256) pk[j] = stg[j];
    if (tid < NPB) lcnt[tid] = 0;
    __syncthreads();
    for (int j = tid; j < bsize; j += 256)
        atomicAdd(&lcnt[pk[j] >> 16], 1);
    __syncthreads();
    if (tid < 64) {                                   // wave-0 scan (NPB=32)
        int v = (tid < NPB) ? lcnt[tid] : 0;
        #pragma unroll
        for (int off = 1; off < NPB; off <<= 1) {
            int u = __shfl_up(v, off);
            if (tid >= off) v += u;
        }
        if (tid < NPB) lbase[tid + 1] = v;
        if (tid == 0) lbase[0] = 0;
    }
    if (tid >= 64 && tid < 64 + NPB) lcur[tid - 64] = 0;
    __syncthreads();
    for (int j = tid; j < bsize; j += 256) {
        u32 w = pk[j];
        int ld = w >> 16;
        int pos = lbase[ld] + atomicAdd(&lcur[ld], 1);
        ssrc[pos] = (unsigned short)(w & 0xFFFFu);
    }
    __syncthreads();                                  // pk dead; evals alias live

    const int q = lane >> 4, ql = lane & 15;
    const float4 b4 = ((const float4*)bias)[ql];
    #pragma unroll
    for (int rnd = 0; rnd < 2; ++rnd) {
        const int ln = rnd * 16 + wv * 4 + q;
        if (ln >= nNodes) continue;
        const int n = node0 + ln;
        const int st = lbase[ln], deg = lbase[ln + 1] - st;
        const float ad = a_dst[n];
        float es = a_src[n] + ad; es = es > 0.f ? es : SLOPE * es;
        const float ps = __expf(es);                  // self-loop term
        float sum = 0.f;
        for (int j = ql; j < deg; j += 16) {
            int s = ssrc[st + j];
            float e = a_src[s] + ad; e = e > 0.f ? e : SLOPE * e;
            float pe = __expf(e);
            evals[st + j] = pe;
            sum += pe;
        }
        sum += __shfl_xor(sum, 8); sum += __shfl_xor(sum, 4);
        sum += __shfl_xor(sum, 2); sum += __shfl_xor(sum, 1);
        const float inv = 1.f / (sum + ps);

        ushort4 hs = h4[(size_t)n * 16 + ql];
        float a0 = ps * bf2f(hs.x), a1 = ps * bf2f(hs.y);
        float a2 = ps * bf2f(hs.z), a3 = ps * bf2f(hs.w);
        int j = 0;
        for (; j + 4 <= deg; j += 4) {                // 4 gathers in flight
            int s0 = ssrc[st + j], s1 = ssrc[st + j + 1];
            int s2 = ssrc[st + j + 2], s3 = ssrc[st + j + 3];
            float e0 = evals[st + j], e1 = evals[st + j + 1];
            float e2 = evals[st + j + 2], e3 = evals[st + j + 3];
            ushort4 v0 = h4[(size_t)s0 * 16 + ql];
            ushort4 v1 = h4[(size_t)s1 * 16 + ql];
            ushort4 v2 = h4[(size_t)s2 * 16 + ql];
            ushort4 v3 = h4[(size_t)s3 * 16 + ql];
            a0 += e0 * bf2f(v0.x); a1 += e0 * bf2f(v0.y);
            a2 += e0 * bf2f(v0.z); a3 += e0 * bf2f(v0.w);
            a0 += e1 * bf2f(v1.x); a1 += e1 * bf2f(v1.y);
            a2 += e1 * bf2f(v1.z); a3 += e1 * bf2f(v1.w);
            a0 += e2 * bf2f(v2.x); a1 += e2 * bf2f(v2.y);
            a2 += e2 * bf2f(v2.z); a3 += e2 * bf2f(v2.w);
            a0 += e3 * bf2f(v3.x); a1 += e3 * bf2f(v3.y);
            a2 += e3 * bf2f(v3.z); a3 += e3 * bf2f(v3.w);
        }
        for (; j < deg; ++j) {
            int s = ssrc[st + j];
            float ev = evals[st + j];
            ushort4 hv = h4[(size_t)s * 16 + ql];
            a0 += ev * bf2f(hv.x); a1 += ev * bf2f(hv.y);
            a2 += ev * bf2f(hv.z); a3 += ev * bf2f(hv.w);
        }
        float4 o;
        o.x = a0 * inv + b4.x; o.x = o.x > 0.f ? o.x : 0.f;
        o.y = a1 * inv + b4.y; o.y = o.y > 0.f ? o.y : 0.f;
        o.z = a2 * inv + b4.z; o.z = o.z > 0.f ? o.z : 0.f;
        o.w = a3 * inv + b4.w; o.w = o.w > 0.f ? o.w : 0.f;
        ((float4*)out)[(size_t)n * 16 + ql] = o;
    }
}

extern "C" void kernel_launch(void* const* d_in, const int* in_sizes, int n_in,
                              void* d_out, int out_size, void* d_ws, size_t ws_size,
                              hipStream_t stream) {
    const float* x     = (const float*)d_in[0];
    const int*   ei    = (const int*)d_in[1];     // int32 (harness converts)
    const float* W     = (const float*)d_in[2];
    const float* att_s = (const float*)d_in[3];
    const float* att_d = (const float*)d_in[4];
    const float* bias  = (const float*)d_in[5];
    float* out = (float*)d_out;

    // ws: h[NN*64] bf16 (6.4MB) | a_src | a_dst (0.4MB) | ccur[64] | fcur[1600]
    //     | cstage[63*27500] u32 (6.9MB) | fstage[1575*1536] u32 (9.7MB)
    unsigned short* h = (unsigned short*)d_ws;
    float* a_src  = (float*)(h + (size_t)NN * 64);
    float* a_dst  = a_src + NN;
    int*   ccur   = (int*)(a_dst + NN);
    int*   fcur   = ccur + 64;
    u32*   cstage = (u32*)(fcur + 1600);
    u32*   fstage = cstage + (size_t)NBC * CAPC;

    hipMemsetAsync(ccur, 0, (64 + 1600) * sizeof(int), stream);  // ccur+fcur

    fused_k<<<FBLK + GBLK, 256, 0, stream>>>(x, W, att_s, att_d, ei, ccur,
                                             cstage, h, a_src, a_dst);
    fine_k<<<NBC * K2PB, 256, 0, stream>>>(cstage, ccur, fcur, fstage);
    agg_k<<<NBF, 256, 0, stream>>>(fstage, fcur, a_src, a_dst,
                                   (const ushort4*)h, bias, out);
}

// Round 14
// 143.782 us; speedup vs baseline: 1.0397x; 1.0283x over previous
//
#include <hip/hip_runtime.h>

#define NN 50000
#define NE 1600000
#define FIN 128
#define FOUT 64
#define SLOPE 0.2f

#define NBC  63              // coarse bins, 800 nodes each (63*800 = 50400)
#define NPC  800
#define CAPC 27500           // coarse cap (mean 25397, sd ~159 -> +13 sigma)
#define NPB  16              // nodes per fine bucket
#define NFPB 50              // fine buckets per coarse bin (800 = 50*16)
#define NBF  (NBC * NFPB)    // 3150 fine buckets
#define CAPB 768             // fine cap (mean 512, sd ~23 -> +11 sigma)
#define FBLK 261             // coarse-fill blocks (R10 best)
#define CHC4 1536            // int4 edge-quads per coarse-fill block (6144 edges)
#define GBLK 782             // gemm blocks, 64 nodes each
#define K2PB 8               // fine blocks per coarse bin (504 total)
#define LW   136             // gemm LDS row stride in bf16 units (272 B)

typedef unsigned int u32;
typedef short short8 __attribute__((ext_vector_type(8)));
typedef float f32x4 __attribute__((ext_vector_type(4)));

__device__ __forceinline__ unsigned short f2bf(float f) {   // RTNE
    u32 u = __float_as_uint(f);
    u += 0x7FFFu + ((u >> 16) & 1u);
    return (unsigned short)(u >> 16);
}
__device__ __forceinline__ float bf2f(unsigned short s) {
    return __uint_as_float(((u32)s) << 16);
}

union FusedLds {
    unsigned short Wt[64 * LW];                       // 17.4 KB (gemm branch)
    struct { int cnt[4][64]; int gb[64]; int cur[64]; } f;  // 1.5 KB (fill)
};

// blocks [0, FBLK): coarse radix — bin edges by dst/800 into 63 bins, packed
//   src | (dstLocal<<16). Per-wave LDS counts, one global atomic per bin,
//   BLOCK-level scatter cursors (R12 lesson: per-wave cursors -> sub-line runs).
// blocks [FBLK, ..): h = x@W bf16 MFMA + a_src/a_dst (fp32 acc)
__global__ __launch_bounds__(256) void fused_k(
        const float* __restrict__ x, const float* __restrict__ W,
        const float* __restrict__ att_s, const float* __restrict__ att_d,
        const int* __restrict__ ei, int* __restrict__ ccur,
        u32* __restrict__ cstage, unsigned short* __restrict__ h,
        float* __restrict__ a_src, float* __restrict__ a_dst) {
    __shared__ FusedLds L;
    const int tid = threadIdx.x;

    if (blockIdx.x < FBLK) {
        const int wv = tid >> 6;
        ((int*)L.f.cnt)[tid] = 0;                     // 256 ints exactly
        __syncthreads();
        const int4* sd4 = (const int4*)(ei + NE);
        const int4* ss4 = (const int4*)ei;
        const int lo = blockIdx.x * CHC4, hi = min(NE / 4, lo + CHC4);
        for (int i = lo + tid; i < hi; i += 256) {
            int4 d = sd4[i];
            atomicAdd(&L.f.cnt[wv][d.x / NPC], 1);
            atomicAdd(&L.f.cnt[wv][d.y / NPC], 1);
            atomicAdd(&L.f.cnt[wv][d.z / NPC], 1);
            atomicAdd(&L.f.cnt[wv][d.w / NPC], 1);
        }
        __syncthreads();
        if (tid < NBC) {
            int tot = L.f.cnt[0][tid] + L.f.cnt[1][tid]
                    + L.f.cnt[2][tid] + L.f.cnt[3][tid];
            L.f.gb[tid] = tot ? atomicAdd(&ccur[tid], tot) : 0;
            L.f.cur[tid] = 0;
        }
        __syncthreads();
        for (int i = lo + tid; i < hi; i += 256) {
            int4 d = sd4[i];
            int4 s = ss4[i];
            int b, pos;
            b = d.x / NPC; pos = L.f.gb[b] + atomicAdd(&L.f.cur[b], 1);
            if (pos < CAPC) cstage[b * CAPC + pos] = (u32)s.x | ((u32)(d.x - b * NPC) << 16);
            b = d.y / NPC; pos = L.f.gb[b] + atomicAdd(&L.f.cur[b], 1);
            if (pos < CAPC) cstage[b * CAPC + pos] = (u32)s.y | ((u32)(d.y - b * NPC) << 16);
            b = d.z / NPC; pos = L.f.gb[b] + atomicAdd(&L.f.cur[b], 1);
            if (pos < CAPC) cstage[b * CAPC + pos] = (u32)s.z | ((u32)(d.z - b * NPC) << 16);
            b = d.w / NPC; pos = L.f.gb[b] + atomicAdd(&L.f.cur[b], 1);
            if (pos < CAPC) cstage[b * CAPC + pos] = (u32)s.w | ((u32)(d.w - b * NPC) << 16);
        }
    } else {
        unsigned short* Wt = L.Wt;
        const int node0 = (blockIdx.x - FBLK) * 64;
        for (int i = tid; i < 128 * 16; i += 256) {   // stage W^T as bf16
            int k = i >> 4, f = (i & 15) * 4;
            float4 w4 = ((const float4*)W)[i];        // W[k][f..f+3]
            Wt[(f + 0) * LW + k] = f2bf(w4.x);
            Wt[(f + 1) * LW + k] = f2bf(w4.y);
            Wt[(f + 2) * LW + k] = f2bf(w4.z);
            Wt[(f + 3) * LW + k] = f2bf(w4.w);
        }
        const int wv = tid >> 6, lane = tid & 63;
        const int q = lane >> 4, mr = lane & 15;
        const int row = node0 + wv * 16 + mr;
        const bool valid = row < NN;
        const float4* x4 = (const float4*)x;

        short8 afr[4];                                // A-frags direct from global
        #pragma unroll
        for (int ks = 0; ks < 4; ++ks) {
            float4 f0 = make_float4(0.f, 0.f, 0.f, 0.f), f1 = f0;
            if (valid) {
                f0 = x4[(size_t)row * 32 + ks * 8 + q * 2];
                f1 = x4[(size_t)row * 32 + ks * 8 + q * 2 + 1];
            }
            short8 a;
            a[0] = (short)f2bf(f0.x); a[1] = (short)f2bf(f0.y);
            a[2] = (short)f2bf(f0.z); a[3] = (short)f2bf(f0.w);
            a[4] = (short)f2bf(f1.x); a[5] = (short)f2bf(f1.y);
            a[6] = (short)f2bf(f1.z); a[7] = (short)f2bf(f1.w);
            afr[ks] = a;
        }
        __syncthreads();

        f32x4 acc[4] = {{0,0,0,0},{0,0,0,0},{0,0,0,0},{0,0,0,0}};
        #pragma unroll
        for (int ks = 0; ks < 4; ++ks) {
            #pragma unroll
            for (int nt = 0; nt < 4; ++nt) {
                short8 b = *(const short8*)(Wt + (nt * 16 + mr) * LW + ks * 32 + q * 8);
                acc[nt] = __builtin_amdgcn_mfma_f32_16x16x32_bf16(afr[ks], b, acc[nt], 0, 0, 0);
            }
        }
        float atts[4], attd[4];
        #pragma unroll
        for (int nt = 0; nt < 4; ++nt) {
            atts[nt] = att_s[nt * 16 + mr];
            attd[nt] = att_d[nt * 16 + mr];
        }
        #pragma unroll
        for (int r = 0; r < 4; ++r) {
            int node = node0 + wv * 16 + q * 4 + r;   // C-layout row
            float ps = 0.f, pd = 0.f;
            #pragma unroll
            for (int nt = 0; nt < 4; ++nt) {
                float v = acc[nt][r];
                if (node < NN) h[(size_t)node * 64 + nt * 16 + mr] = f2bf(v);
                ps += v * atts[nt];
                pd += v * attd[nt];
            }
            #pragma unroll
            for (int off = 8; off > 0; off >>= 1) {
                ps += __shfl_xor(ps, off);
                pd += __shfl_xor(pd, off);
            }
            if (mr == 0 && node < NN) { a_src[node] = ps; a_dst[node] = pd; }
        }
    }
}

// pass 2: re-bin each coarse bin into its 50 aligned fine buckets (800=50*16).
// K2PB blocks per bin, disjoint slices; runs ~63 edges = 252 B.
__global__ __launch_bounds__(256) void fine_k(
        const u32* __restrict__ cstage, const int* __restrict__ ccur,
        int* __restrict__ fcur, u32* __restrict__ fstage) {
    const int bin = blockIdx.x / K2PB, sub = blockIdx.x % K2PB;
    const int size = min(ccur[bin], CAPC);
    const int qs = (size + K2PB - 1) / K2PB;
    const int lo = sub * qs, hi = min(size, lo + qs);
    const u32* src = cstage + (size_t)bin * CAPC;
    const int tid = threadIdx.x, wv = tid >> 6;

    __shared__ int cnt[4][64];
    __shared__ int gb[64];
    __shared__ int cur[64];
    ((int*)cnt)[tid] = 0;
    __syncthreads();
    for (int i = lo + tid; i < hi; i += 256)
        atomicAdd(&cnt[wv][(src[i] >> 16) >> 4], 1);
    __syncthreads();
    if (tid < NFPB) {
        int tot = cnt[0][tid] + cnt[1][tid] + cnt[2][tid] + cnt[3][tid];
        gb[tid] = tot ? atomicAdd(&fcur[bin * NFPB + tid], tot) : 0;
        cur[tid] = 0;
    }
    __syncthreads();
    for (int i = lo + tid; i < hi; i += 256) {
        u32 w = src[i];
        int dl = w >> 16;                             // coarse-local dst [0,800)
        int f = dl >> 4;                              // fine bucket in bin [0,50)
        int pos = gb[f] + atomicAdd(&cur[f], 1);
        if (pos < CAPB)
            fstage[(size_t)(bin * NFPB + f) * CAPB + pos] =
                (w & 0xFFFFu) | ((u32)(dl & 15) << 16);
    }
}

// one block per 16-node fine bucket: node-local CSR in LDS, then one 16-lane
// quad per node (lane = 4 features, ushort4 h loads, float4 out store).
// NPB=16: 4.8 KB LDS, 3150 blocks -> max resident waves to hide gather latency.
__global__ __launch_bounds__(256) void agg_k(
        const u32* __restrict__ staging, const int* __restrict__ bcur,
        const float* __restrict__ a_src, const float* __restrict__ a_dst,
        const ushort4* __restrict__ h4, const float* __restrict__ bias,
        float* __restrict__ out) {
    const int bkt = blockIdx.x;
    const int node0 = bkt << 4;
    if (node0 >= NN) return;                          // tail buckets (>50000)
    const int nNodes = min(NPB, NN - node0);
    const int bsize = min(bcur[bkt], CAPB);
    const u32* stg = staging + (size_t)bkt * CAPB;
    const int tid = threadIdx.x, wv = tid >> 6, lane = tid & 63;

    __shared__ u32 pk[CAPB];                          // packed; aliased as evals
    __shared__ unsigned short ssrc[CAPB];
    __shared__ int lcnt[NPB];
    __shared__ int lbase[NPB + 1];
    __shared__ int lcur[NPB];
    float* evals = (float*)pk;

    for (int j = tid; j < bsize; j += 256) pk[j] = stg[j];
    if (tid < NPB) lcnt[tid] = 0;
    __syncthreads();
    for (int j = tid; j < bsize; j += 256)
        atomicAdd(&lcnt[pk[j] >> 16], 1);
    __syncthreads();
    if (tid < 64) {                                   // wave-0 scan (NPB=16)
        int v = (tid < NPB) ? lcnt[tid] : 0;
        #pragma unroll
        for (int off = 1; off < NPB; off <<= 1) {
            int u = __shfl_up(v, off);
            if (tid >= off) v += u;
        }
        if (tid < NPB) lbase[tid + 1] = v;
        if (tid == 0) lbase[0] = 0;
    }
    if (tid >= 64 && tid < 64 + NPB) lcur[tid - 64] = 0;
    __syncthreads();
    for (int j = tid; j < bsize; j += 256) {
        u32 w = pk[j];
        int ld = w >> 16;
        int pos = lbase[ld] + atomicAdd(&lcur[ld], 1);
        ssrc[pos] = (unsigned short)(w & 0xFFFFu);
    }
    __syncthreads();                                  // pk dead; evals alias live

    const int q = lane >> 4, ql = lane & 15;
    const float4 b4 = ((const float4*)bias)[ql];
    const int ln = wv * 4 + q;                        // quad-uniform node [0,16)
    if (ln >= nNodes) return;
    const int n = node0 + ln;
    const int st = lbase[ln], deg = lbase[ln + 1] - st;
    const float ad = a_dst[n];
    float es = a_src[n] + ad; es = es > 0.f ? es : SLOPE * es;
    const float ps = __expf(es);                      // self-loop term
    float sum = 0.f;
    for (int j = ql; j < deg; j += 16) {
        int s = ssrc[st + j];
        float e = a_src[s] + ad; e = e > 0.f ? e : SLOPE * e;
        float pe = __expf(e);
        evals[st + j] = pe;
        sum += pe;
    }
    sum += __shfl_xor(sum, 8); sum += __shfl_xor(sum, 4);
    sum += __shfl_xor(sum, 2); sum += __shfl_xor(sum, 1);
    const float inv = 1.f / (sum + ps);

    ushort4 hs = h4[(size_t)n * 16 + ql];
    float a0 = ps * bf2f(hs.x), a1 = ps * bf2f(hs.y);
    float a2 = ps * bf2f(hs.z), a3 = ps * bf2f(hs.w);
    int j = 0;
    for (; j + 4 <= deg; j += 4) {                    // 4 gathers in flight
        int s0 = ssrc[st + j], s1 = ssrc[st + j + 1];
        int s2 = ssrc[st + j + 2], s3 = ssrc[st + j + 3];
        float e0 = evals[st + j], e1 = evals[st + j + 1];
        float e2 = evals[st + j + 2], e3 = evals[st + j + 3];
        ushort4 v0 = h4[(size_t)s0 * 16 + ql];
        ushort4 v1 = h4[(size_t)s1 * 16 + ql];
        ushort4 v2 = h4[(size_t)s2 * 16 + ql];
        ushort4 v3 = h4[(size_t)s3 * 16 + ql];
        a0 += e0 * bf2f(v0.x); a1 += e0 * bf2f(v0.y);
        a2 += e0 * bf2f(v0.z); a3 += e0 * bf2f(v0.w);
        a0 += e1 * bf2f(v1.x); a1 += e1 * bf2f(v1.y);
        a2 += e1 * bf2f(v1.z); a3 += e1 * bf2f(v1.w);
        a0 += e2 * bf2f(v2.x); a1 += e2 * bf2f(v2.y);
        a2 += e2 * bf2f(v2.z); a3 += e2 * bf2f(v2.w);
        a0 += e3 * bf2f(v3.x); a1 += e3 * bf2f(v3.y);
        a2 += e3 * bf2f(v3.z); a3 += e3 * bf2f(v3.w);
    }
    for (; j < deg; ++j) {
        int s = ssrc[st + j];
        float ev = evals[st + j];
        ushort4 hv = h4[(size_t)s * 16 + ql];
        a0 += ev * bf2f(hv.x); a1 += ev * bf2f(hv.y);
        a2 += ev * bf2f(hv.z); a3 += ev * bf2f(hv.w);
    }
    float4 o;
    o.x = a0 * inv + b4.x; o.x = o.x > 0.f ? o.x : 0.f;
    o.y = a1 * inv + b4.y; o.y = o.y > 0.f ? o.y : 0.f;
    o.z = a2 * inv + b4.z; o.z = o.z > 0.f ? o.z : 0.f;
    o.w = a3 * inv + b4.w; o.w = o.w > 0.f ? o.w : 0.f;
    ((float4*)out)[(size_t)n * 16 + ql] = o;
}

extern "C" void kernel_launch(void* const* d_in, const int* in_sizes, int n_in,
                              void* d_out, int out_size, void* d_ws, size_t ws_size,
                              hipStream_t stream) {
    const float* x     = (const float*)d_in[0];
    const int*   ei    = (const int*)d_in[1];     // int32 (harness converts)
    const float* W     = (const float*)d_in[2];
    const float* att_s = (const float*)d_in[3];
    const float* att_d = (const float*)d_in[4];
    const float* bias  = (const float*)d_in[5];
    float* out = (float*)d_out;

    // ws: h[NN*64] bf16 (6.4MB) | a_src | a_dst (0.4MB) | ccur[64] | fcur[3200]
    //     | cstage[63*27500] u32 (6.9MB) | fstage[3150*768] u32 (9.7MB)
    unsigned short* h = (unsigned short*)d_ws;
    float* a_src  = (float*)(h + (size_t)NN * 64);
    float* a_dst  = a_src + NN;
    int*   ccur   = (int*)(a_dst + NN);
    int*   fcur   = ccur + 64;
    u32*   cstage = (u32*)(fcur + 3200);
    u32*   fstage = cstage + (size_t)NBC * CAPC;

    hipMemsetAsync(ccur, 0, (64 + 3200) * sizeof(int), stream);  // ccur+fcur

    fused_k<<<FBLK + GBLK, 256, 0, stream>>>(x, W, att_s, att_d, ei, ccur,
                                             cstage, h, a_src, a_dst);
    fine_k<<<NBC * K2PB, 256, 0, stream>>>(cstage, ccur, fcur, fstage);
    agg_k<<<NBF, 256, 0, stream>>>(fstage, fcur, a_src, a_dst,
                                   (const ushort4*)h, bias, out);
}